// Round 1
// 4083.383 us; speedup vs baseline: 1.0392x; 1.0392x over previous
//
#include <hip/hip_runtime.h>
#include <stdint.h>

typedef unsigned short u16;
typedef short v8s __attribute__((ext_vector_type(8)));
typedef float v4f __attribute__((ext_vector_type(4)));

#define DI static __device__ __forceinline__

DI u16 f2bf(float x){ union{float f; uint32_t u;} c; c.f = x; uint32_t r = c.u + 0x7fffu + ((c.u >> 16) & 1u); return (u16)(r >> 16); }
DI float bf2f(u16 b){ union{float f; uint32_t u;} c; c.u = ((uint32_t)b) << 16; return c.f; }
DI float gelu_f(float x){ return 0.5f * x * (1.0f + erff(x * 0.70710678118654752f)); }
DI float sigm(float x){ return 1.0f / (1.0f + expf(-x)); }

DI float gru_out(float i0, float i1, float i2, float g0, float g1, float g2,
                 float b0, float b1, float b2, float hprev)
{
    float r = sigm(i0 + g0 + b0);
    float z = sigm(i1 + g1 + b1);
    float n = tanhf(i2 + r * (g2 + b2));
    return (1.f - z) * n + z * hprev;
}

// ---------------------------------------------------------------------------
// Transpose + bf16 hi/lo split: W (K x N, f32) -> hi,lo (N x K, bf16 bits)
// ---------------------------------------------------------------------------
__global__ __launch_bounds__(256) void transpose_split_kernel(
    const float* __restrict__ W, u16* __restrict__ hi, u16* __restrict__ lo, int K, int N)
{
    __shared__ float t[32][33];
    int n0 = blockIdx.x * 32, k0 = blockIdx.y * 32;
    int tx = threadIdx.x & 31, ty = threadIdx.x >> 5; // 32 x 8
    #pragma unroll
    for (int i = 0; i < 4; i++) {
        int k = k0 + ty + i * 8, n = n0 + tx;
        float v = (k < K && n < N) ? W[(size_t)k * N + n] : 0.f;
        t[ty + i * 8][tx] = v;
    }
    __syncthreads();
    #pragma unroll
    for (int i = 0; i < 4; i++) {
        int n = n0 + ty + i * 8, k = k0 + tx;
        if (n < N && k < K) {
            float v = t[tx][ty + i * 8];
            u16 h = f2bf(v);
            hi[(size_t)n * K + k] = h;
            lo[(size_t)n * K + k] = f2bf(v - bf2f(h));
        }
    }
}

// Plain f32 transpose: W (K x N) -> WT (N x K)
__global__ __launch_bounds__(256) void transpose_f32_kernel(
    const float* __restrict__ W, float* __restrict__ WT, int K, int N)
{
    __shared__ float t[32][33];
    int n0 = blockIdx.x * 32, k0 = blockIdx.y * 32;
    int tx = threadIdx.x & 31, ty = threadIdx.x >> 5;
    #pragma unroll
    for (int i = 0; i < 4; i++) {
        int k = k0 + ty + i * 8, n = n0 + tx;
        t[ty + i * 8][tx] = (k < K && n < N) ? W[(size_t)k * N + n] : 0.f;
    }
    __syncthreads();
    #pragma unroll
    for (int i = 0; i < 4; i++) {
        int n = n0 + ty + i * 8, k = k0 + tx;
        if (n < N && k < K) WT[(size_t)n * K + k] = t[tx][ty + i * 8];
    }
}

// ---------------------------------------------------------------------------
// Embedding gathers + zero-init h buffers + zero grid-barrier counters
// blocks: [0,2048) enc rows, [2048,4064) dec rows, [4064,4192) zero h, 4192 bar
// ---------------------------------------------------------------------------
__global__ __launch_bounds__(256) void gather_init_kernel(
    const int* __restrict__ src, const int* __restrict__ trg,
    const float* __restrict__ enc_embed, const float* __restrict__ dec_embed,
    float* __restrict__ embE, float* __restrict__ embD,
    float* __restrict__ hF0, float* __restrict__ hB0,
    unsigned* __restrict__ bar)
{
    int r = blockIdx.x, tx = threadIdx.x;
    if (r < 2048) {
        int idx = src[r];
        embE[(size_t)r * 256 + tx] = enc_embed[(size_t)idx * 256 + tx];
    } else if (r < 4064) {
        int rd = r - 2048;
        int t = rd >> 5, b = rd & 31;
        int tok = trg[b * 64 + t];
        embD[(size_t)rd * 256 + tx] = dec_embed[(size_t)tok * 256 + tx];
    } else if (r < 4192) {
        int i = (r - 4064) * 256 + tx; // [0, 32768)
        if (i < 16384) hF0[i] = 0.f; else hB0[i - 16384] = 0.f;
    } else {
        if (tx < 16) bar[tx] = 0u;
    }
}

// ---------------------------------------------------------------------------
// GEMM: C = act(A @ B + bias).  B pre-transposed, bf16-split (N x K hi/lo).
// 3-MFMA compensated product.  128x128 tile, BK=32, 256 thr = 4 waves.
// swz: XCD-contiguous remap (n-tile per XCD, m fastest) for B-tile L2 reuse.
// ---------------------------------------------------------------------------
__global__ __launch_bounds__(256) void gemm_bf16x3_kernel(
    const float* __restrict__ A, const u16* __restrict__ Bhi, const u16* __restrict__ Blo,
    const float* __restrict__ bias, float* __restrict__ C,
    int M, int N, int K, int act_gelu, int remap, int swz)
{
    __shared__ u16 Ah[128 * 40], Al[128 * 40], Bh[128 * 40], Bl[128 * 40];
    const int tid = threadIdx.x;
    const int lane = tid & 63, wave = tid >> 6;
    const int lm = lane & 15, quad = lane >> 4;
    const int wm = wave >> 1, wn = wave & 1;
    int tbx = blockIdx.x, tby = blockIdx.y;
    if (swz) {
        int nb = gridDim.x * gridDim.y;     // must be % 8 == 0 when swz=1
        int lin = tby * gridDim.x + tbx;
        int per = nb >> 3;
        int g = (lin & 7) * per + (lin >> 3);
        tby = g % gridDim.y;                // m-tile fastest within an XCD
        tbx = g / gridDim.y;
    }
    const int m0 = tby * 128, n0 = tbx * 128;
    const int sr = tid >> 1;          // staging row 0..127
    const int sh = (tid & 1) * 16;    // staging k-offset 0/16

    v4f acc[4][4];
    #pragma unroll
    for (int i = 0; i < 4; i++)
        #pragma unroll
        for (int j = 0; j < 4; j++)
            #pragma unroll
            for (int r = 0; r < 4; r++) acc[i][j][r] = 0.f;

    for (int k0 = 0; k0 < K; k0 += 32) {
        // ---- stage A (f32 -> bf16 hi/lo) ----
        {
            float v[16];
            const int gm = m0 + sr;
            if (gm < M) {
                const float4* p = (const float4*)(A + (size_t)gm * K + k0 + sh);
                #pragma unroll
                for (int i = 0; i < 4; i++) {
                    float4 q = p[i];
                    v[4*i] = q.x; v[4*i+1] = q.y; v[4*i+2] = q.z; v[4*i+3] = q.w;
                }
            } else {
                #pragma unroll
                for (int i = 0; i < 16; i++) v[i] = 0.f;
            }
            v8s h0, h1, l0, l1;
            #pragma unroll
            for (int i = 0; i < 8; i++) {
                u16 ha = f2bf(v[i]);     u16 la = f2bf(v[i] - bf2f(ha));
                u16 hb = f2bf(v[8+i]);   u16 lb = f2bf(v[8+i] - bf2f(hb));
                h0[i] = (short)ha; l0[i] = (short)la; h1[i] = (short)hb; l1[i] = (short)lb;
            }
            *(v8s*)&Ah[sr * 40 + sh] = h0; *(v8s*)&Ah[sr * 40 + sh + 8] = h1;
            *(v8s*)&Al[sr * 40 + sh] = l0; *(v8s*)&Al[sr * 40 + sh + 8] = l1;
        }
        // ---- stage B (already bf16 hi/lo, N x K) ----
        {
            const int gn = n0 + sr;
            v8s b0, b1, c0, c1;
            if (gn < N) {
                const v8s* ph = (const v8s*)(Bhi + (size_t)gn * K + k0 + sh);
                const v8s* pl = (const v8s*)(Blo + (size_t)gn * K + k0 + sh);
                b0 = ph[0]; b1 = ph[1]; c0 = pl[0]; c1 = pl[1];
            } else {
                #pragma unroll
                for (int i = 0; i < 8; i++) { b0[i] = 0; b1[i] = 0; c0[i] = 0; c1[i] = 0; }
            }
            *(v8s*)&Bh[sr * 40 + sh] = b0; *(v8s*)&Bh[sr * 40 + sh + 8] = b1;
            *(v8s*)&Bl[sr * 40 + sh] = c0; *(v8s*)&Bl[sr * 40 + sh + 8] = c1;
        }
        __syncthreads();
        // ---- fragments + MFMA ----
        v8s ah[4], al[4], bh[4], bl[4];
        #pragma unroll
        for (int mt = 0; mt < 4; mt++) {
            int off = (wm * 64 + mt * 16 + lm) * 40 + quad * 8;
            ah[mt] = *(v8s*)&Ah[off]; al[mt] = *(v8s*)&Al[off];
        }
        #pragma unroll
        for (int nt = 0; nt < 4; nt++) {
            int off = (wn * 64 + nt * 16 + lm) * 40 + quad * 8;
            bh[nt] = *(v8s*)&Bh[off]; bl[nt] = *(v8s*)&Bl[off];
        }
        #pragma unroll
        for (int mt = 0; mt < 4; mt++)
            #pragma unroll
            for (int nt = 0; nt < 4; nt++) {
                v4f a = acc[mt][nt];
                a = __builtin_amdgcn_mfma_f32_16x16x32_bf16(ah[mt], bh[nt], a, 0, 0, 0);
                a = __builtin_amdgcn_mfma_f32_16x16x32_bf16(ah[mt], bl[nt], a, 0, 0, 0);
                a = __builtin_amdgcn_mfma_f32_16x16x32_bf16(al[mt], bh[nt], a, 0, 0, 0);
                acc[mt][nt] = a;
            }
        __syncthreads();
    }
    // ---- epilogue ----
    #pragma unroll
    for (int nt = 0; nt < 4; nt++) {
        int col = n0 + wn * 64 + nt * 16 + lm;
        if (col >= N) continue;
        float bv = bias ? bias[col] : 0.f;
        #pragma unroll
        for (int mt = 0; mt < 4; mt++) {
            int rbase = m0 + wm * 64 + mt * 16 + quad * 4;
            #pragma unroll
            for (int r = 0; r < 4; r++) {
                int row = rbase + r;
                if (row < M) {
                    float v = acc[mt][nt][r] + bv;
                    if (act_gelu) v = gelu_f(v);
                    size_t drow = remap ? (size_t)((row & 31) * 64 + (row >> 5) + 1) : (size_t)row;
                    C[drow * (size_t)N + col] = v;
                }
            }
        }
    }
}

// ---------------------------------------------------------------------------
// Device-scope software grid barrier (monotonic counter, per-phase target).
// Launch cooperatively so all blocks are co-resident.  Release: ACQ_REL atomic
// RMW at agent scope (compiler emits L2 writeback).  Acquire: __threadfence
// after spin (emits L1/L2 invalidate) before the block proceeds.
// ---------------------------------------------------------------------------
DI void grid_barrier(unsigned* ctr, unsigned target)
{
    __syncthreads();
    if (threadIdx.x == 0) {
        __hip_atomic_fetch_add(ctr, 1u, __ATOMIC_ACQ_REL, __HIP_MEMORY_SCOPE_AGENT);
        while (__hip_atomic_load(ctr, __ATOMIC_RELAXED, __HIP_MEMORY_SCOPE_AGENT) < target)
            __builtin_amdgcn_s_sleep(2);
        __threadfence();
    }
    __syncthreads();
}

// Stage 24 weight columns (8 j x 3 gates, K=512) into LDS once per kernel.
// Layout: wl[c*512 + (k ^ ((c&7)<<2))]  -> conflict-free b128 reads.
DI void stage_weights(const float* __restrict__ Wh, int jb, int tid, float* wl)
{
    for (int i = tid; i < 24 * 512; i += 256) {
        int k = i / 24, c = i - k * 24;
        wl[c * 512 + (k ^ ((c & 7) << 2))] =
            Wh[(size_t)k * 1536 + (c >> 3) * 512 + jb + (c & 7)];
    }
}

// One GRU gate-dot: g{0,1,2} = h . Wh[:, {j, 512+j, 1024+j}], h staged through
// XOR-swizzled 32x128 LDS tiles, weights from LDS (wl).
DI void gru_gates(const float* __restrict__ hin, float* hl,
                  const float* w0, const float* w1, const float* w2,
                  int tid, int b, int jj, float& g0, float& g1, float& g2)
{
    const int bsw = (b & 7) << 2;
    const int jsw = jj << 2;
    g0 = 0.f; g1 = 0.f; g2 = 0.f;
    for (int kt = 0; kt < 512; kt += 128) {
        __syncthreads();
        #pragma unroll
        for (int w = 0; w < 4; w++) {
            int f4 = tid + w * 256;              // float4 slot in 32x128 tile
            int bb = f4 >> 5;
            int kk = (f4 & 31) * 4;
            float4 v = *(const float4*)(hin + bb * 512 + kt + kk);
            *(float4*)&hl[bb * 128 + (kk ^ ((bb & 7) << 2))] = v;
        }
        __syncthreads();
        const float* w0t = w0 + kt;
        const float* w1t = w1 + kt;
        const float* w2t = w2 + kt;
        const float* hlb = &hl[b * 128];
        #pragma unroll 4
        for (int kk = 0; kk < 128; kk += 4) {
            int ko = kk ^ jsw;
            float4 hv = *(const float4*)&hlb[kk ^ bsw];
            float4 a  = *(const float4*)(w0t + ko);
            float4 c  = *(const float4*)(w1t + ko);
            float4 d  = *(const float4*)(w2t + ko);
            g0 += hv.x * a.x; g1 += hv.x * c.x; g2 += hv.x * d.x;
            g0 += hv.y * a.y; g1 += hv.y * c.y; g2 += hv.y * d.y;
            g0 += hv.z * a.z; g1 += hv.z * c.z; g2 += hv.z * d.z;
            g0 += hv.w * a.w; g1 += hv.w * c.w; g2 += hv.w * d.w;
        }
    }
}

// ---------------------------------------------------------------------------
// Persistent encoder: 128 blocks (64 fwd + 64 bwd), 64 steps, 1 grid barrier
// per step.  Wh columns LDS-resident across all steps.  h ping-pongs in global.
// ---------------------------------------------------------------------------
__global__ __launch_bounds__(256) void enc_persistent_kernel(
    float* __restrict__ hF, float* __restrict__ hB,
    const float* __restrict__ giF, const float* __restrict__ giB,
    const float* __restrict__ Wh_f, const float* __restrict__ Wh_b,
    const float* __restrict__ bh_f, const float* __restrict__ bh_b,
    const int* __restrict__ src_lens,
    float* __restrict__ wrep, float* __restrict__ sent,
    unsigned* __restrict__ bar)
{
    __shared__ float wl[24 * 512];   // 48 KiB
    __shared__ float hl[32 * 128];   // 16 KiB  (total = 64 KiB exactly)
    const int dir = blockIdx.x >> 6;
    const int jb = (blockIdx.x & 63) * 8;
    const int tid = threadIdx.x;
    const int b = tid >> 3, jj = tid & 7, j = jb + jj;
    const float* gi = dir ? giB : giF;
    const float* bh = dir ? bh_b : bh_f;
    float* hbase = dir ? hB : hF;

    stage_weights(dir ? Wh_b : Wh_f, jb, tid, wl);
    int len = src_lens[b]; if (len < 1) len = 1;
    const float bh0 = bh[j], bh1 = bh[512 + j], bh2 = bh[1024 + j];
    const float* w0 = &wl[jj * 512];
    const float* w1 = &wl[(8 + jj) * 512];
    const float* w2 = &wl[(16 + jj) * 512];
    // first __syncthreads inside gru_gates publishes wl

    for (int step = 0; step < 64; step++) {
        const float* hin = hbase + (step & 1) * 16384;
        float* hout = hbase + ((step + 1) & 1) * 16384;
        const int t_eff = dir ? (63 - step) : step;
        float g0, g1, g2;
        gru_gates(hin, hl, w0, w1, w2, tid, b, jj, g0, g1, g2);
        size_t gbase = ((size_t)b * 64 + t_eff) * 1536 + j;
        float hprev = hin[b * 512 + j];
        float hnew = gru_out(gi[gbase], gi[gbase + 512], gi[gbase + 1024],
                             g0, g1, g2, bh0, bh1, bh2, hprev);
        bool valid = t_eff < len;
        float hkeep = valid ? hnew : hprev;
        hout[b * 512 + j] = hkeep;
        wrep[((size_t)b * 64 + t_eff) * 1024 + dir * 512 + j] = valid ? hnew : 0.f;
        if (step == 63) sent[b * 1024 + dir * 512 + j] = hkeep;
        else grid_barrier(bar, 128u * (unsigned)(step + 1));
    }
}

// ---------------------------------------------------------------------------
// Persistent decoder: 64 blocks, 63 steps.  Phase A: GRU cell (8 j-cols per
// block, Wh_d LDS-resident).  Phase B: attention (block pair per batch row).
// Two grid barriers per step.
// ---------------------------------------------------------------------------
__global__ __launch_bounds__(256) void dec_persistent_kernel(
    float* __restrict__ HID, const float* __restrict__ giD,
    const float* __restrict__ Wh_d, const float* __restrict__ bh_d,
    const float* __restrict__ Kmat, const float* __restrict__ Vmat,
    const float* __restrict__ WqT, const float* __restrict__ bq,
    float* __restrict__ htmp, unsigned* __restrict__ bar)
{
    __shared__ float wl[24 * 512];
    __shared__ float pool[32 * 128];   // phase A: h tile; phase B: hb/qp/qv/aw
    const int bx = blockIdx.x, tid = threadIdx.x;
    const int b = tid >> 3, jj = tid & 7, j = bx * 8 + jj;
    const int bb = bx >> 1, half = bx & 1;
    float* hb = pool;          // 512
    float* qp = pool + 512;    // 256
    float* qv = pool + 768;    // 64
    float* aw = pool + 832;    // 64

    stage_weights(Wh_d, bx * 8, tid, wl);
    const float bh0 = bh_d[j], bh1 = bh_d[512 + j], bh2 = bh_d[1024 + j];
    const float* w0 = &wl[jj * 512];
    const float* w1 = &wl[(8 + jj) * 512];
    const float* w2 = &wl[(16 + jj) * 512];

    for (int t = 0; t < 63; t++) {
        // ---- phase A: h_t = GRU(e_t, hid_{t-1}) -> htmp ----
        const float* hin = HID + (size_t)t * 16384;
        float g0, g1, g2;
        gru_gates(hin, pool, w0, w1, w2, tid, b, jj, g0, g1, g2);
        size_t gbase = ((size_t)t * 32 + b) * 1536 + j;
        float hprev = hin[b * 512 + j];
        float hnew = gru_out(giD[gbase], giD[gbase + 512], giD[gbase + 1024],
                             g0, g1, g2, bh0, bh1, bh2, hprev);
        htmp[b * 512 + j] = hnew;
        grid_barrier(bar, 64u * (unsigned)(2 * t + 1));

        // ---- phase B: attention; block pair (bb, half) ----
        hb[tid] = htmp[bb * 512 + tid];
        hb[256 + tid] = htmp[bb * 512 + 256 + tid];
        __syncthreads();
        {   // q = h @ Wq, 4-way K-split per output
            int o = tid >> 2, part = tid & 3;
            const float* wq = WqT + (size_t)o * 512 + part * 128;
            const float* hh = hb + part * 128;
            float acc = 0.f;
            #pragma unroll 4
            for (int k = 0; k < 128; k += 4) {
                float4 w = *(const float4*)(wq + k);
                acc += hh[k]*w.x + hh[k+1]*w.y + hh[k+2]*w.z + hh[k+3]*w.w;
            }
            qp[tid] = acc;
        }
        __syncthreads();
        if (tid < 64) qv[tid] = qp[tid*4] + qp[tid*4+1] + qp[tid*4+2] + qp[tid*4+3] + bq[tid];
        __syncthreads();
        if (tid < 64) {
            const float* kr = Kmat + ((size_t)bb * 64 + tid) * 64;
            float sc = 0.f;
            #pragma unroll
            for (int d = 0; d < 64; d += 4) {
                float4 kv = *(const float4*)(kr + d);
                sc += qv[d]*kv.x + qv[d+1]*kv.y + qv[d+2]*kv.z + qv[d+3]*kv.w;
            }
            sc *= 0.125f; // 1/sqrt(64)
            float mx = sc;
            #pragma unroll
            for (int m = 32; m >= 1; m >>= 1) mx = fmaxf(mx, __shfl_xor(mx, m));
            float e = expf(sc - mx);
            float sm = e;
            #pragma unroll
            for (int m = 32; m >= 1; m >>= 1) sm += __shfl_xor(sm, m);
            aw[tid] = e / sm;
        }
        __syncthreads();
        {   // hid = h + alpha @ V   (this block: 256 of 512 columns)
            int jcol = half * 256 + tid;
            const float* vp = Vmat + (size_t)bb * 32768 + jcol;
            float acc = 0.f;
            #pragma unroll 8
            for (int s = 0; s < 64; s++) acc += aw[s] * vp[(size_t)s * 512];
            HID[(size_t)(t + 1) * 16384 + (size_t)bb * 512 + jcol] = hb[jcol] + acc;
        }
        if (t < 62) grid_barrier(bar, 64u * (unsigned)(2 * t + 2));
    }
}

// out[:, 0, :] = 0
__global__ __launch_bounds__(256) void zero_col0_kernel(float* __restrict__ out)
{
    int gid = blockIdx.x * 256 + threadIdx.x;
    if (gid < 32 * 32000) {
        int b = gid / 32000, col = gid % 32000;
        out[(size_t)b * 64 * 32000 + col] = 0.f;
    }
}

// ---------------------------------------------------------------------------
extern "C" void kernel_launch(void* const* d_in, const int* in_sizes, int n_in,
                              void* d_out, int out_size, void* d_ws, size_t ws_size,
                              hipStream_t stream)
{
    const int*   src       = (const int*)d_in[0];
    const int*   trg       = (const int*)d_in[1];
    const int*   src_lens  = (const int*)d_in[2];
    const float* enc_embed = (const float*)d_in[3];
    const float* Wi_f  = (const float*)d_in[4];
    const float* Wh_f  = (const float*)d_in[5];
    const float* bi_f  = (const float*)d_in[6];
    const float* bh_f  = (const float*)d_in[7];
    const float* Wi_b  = (const float*)d_in[8];
    const float* Wh_b  = (const float*)d_in[9];
    const float* bi_b  = (const float*)d_in[10];
    const float* bh_b  = (const float*)d_in[11];
    const float* W_e2d = (const float*)d_in[12];
    const float* b_e2d = (const float*)d_in[13];
    const float* dec_embed = (const float*)d_in[14];
    const float* Wi_d  = (const float*)d_in[15];
    const float* Wh_d  = (const float*)d_in[16];
    const float* bi_d  = (const float*)d_in[17];
    const float* bh_d  = (const float*)d_in[18];
    const float* Wq    = (const float*)d_in[19];
    const float* bq    = (const float*)d_in[20];
    const float* Wk    = (const float*)d_in[21];
    const float* bk    = (const float*)d_in[22];
    const float* Wv    = (const float*)d_in[23];
    const float* bv    = (const float*)d_in[24];
    const float* W1    = (const float*)d_in[25];
    const float* b1    = (const float*)d_in[26];
    const float* W2    = (const float*)d_in[27];
    const float* b2    = (const float*)d_in[28];
    float* out = (float*)d_out;

    // workspace layout (~135 MB)
    float* f = (float*)d_ws;
    float* embE = f; f += 524288;     // 2048 x 256
    float* embD = f; f += 516096;     // 2016 x 256
    float* giF  = f; f += 3145728;    // 2048 x 1536
    float* giB  = f; f += 3145728;
    float* giD  = f; f += 3096576;    // 2016 x 1536
    float* wrep = f; f += 2097152;    // 2048 x 1024
    float* sent = f; f += 32768;      // 32 x 1024
    float* hF   = f; f += 32768;      // 2 x 32 x 512 ping-pong
    float* hB   = f; f += 32768;
    float* Kmat = f; f += 131072;     // 2048 x 64
    float* Vmat = f; f += 1048576;    // 2048 x 512
    float* HID  = f; f += 1048576;    // 64 x 32 x 512 (slot 0 = hidden0)
    float* htmp = f; f += 16384;      // 32 x 512
    float* G1   = f; f += 1032192;    // 2016 x 512
    float* WqT  = f; f += 32768;      // 64 x 512 (Wq transposed, f32)
    unsigned* bar = (unsigned*)f; f += 16;  // grid-barrier counters
    u16* u = (u16*)f;
    u16* WiF_hi = u; u += 393216;  u16* WiF_lo = u; u += 393216;  // 1536 x 256
    u16* WiB_hi = u; u += 393216;  u16* WiB_lo = u; u += 393216;
    u16* WiD_hi = u; u += 393216;  u16* WiD_lo = u; u += 393216;
    u16* Wk_hi  = u; u += 65536;   u16* Wk_lo  = u; u += 65536;   // 64 x 1024
    u16* Wv_hi  = u; u += 524288;  u16* Wv_lo  = u; u += 524288;  // 512 x 1024
    u16* We_hi  = u; u += 524288;  u16* We_lo  = u; u += 524288;  // 512 x 1024
    u16* W1_hi  = u; u += 262144;  u16* W1_lo  = u; u += 262144;  // 512 x 512
    u16* W2_hi  = u; u += 16384000; u16* W2_lo = u; u += 16384000; // 32000 x 512

    // --- weight transpose + bf16 split (+ f32 Wq transpose) ---
    hipLaunchKernelGGL(transpose_split_kernel, dim3(48, 8),   dim3(256), 0, stream, Wi_f,  WiF_hi, WiF_lo, 256, 1536);
    hipLaunchKernelGGL(transpose_split_kernel, dim3(48, 8),   dim3(256), 0, stream, Wi_b,  WiB_hi, WiB_lo, 256, 1536);
    hipLaunchKernelGGL(transpose_split_kernel, dim3(48, 8),   dim3(256), 0, stream, Wi_d,  WiD_hi, WiD_lo, 256, 1536);
    hipLaunchKernelGGL(transpose_split_kernel, dim3(2, 32),   dim3(256), 0, stream, Wk,    Wk_hi,  Wk_lo,  1024, 64);
    hipLaunchKernelGGL(transpose_split_kernel, dim3(16, 32),  dim3(256), 0, stream, Wv,    Wv_hi,  Wv_lo,  1024, 512);
    hipLaunchKernelGGL(transpose_split_kernel, dim3(16, 32),  dim3(256), 0, stream, W_e2d, We_hi,  We_lo,  1024, 512);
    hipLaunchKernelGGL(transpose_split_kernel, dim3(16, 16),  dim3(256), 0, stream, W1,    W1_hi,  W1_lo,  512, 512);
    hipLaunchKernelGGL(transpose_split_kernel, dim3(1000, 16),dim3(256), 0, stream, W2,    W2_hi,  W2_lo,  512, 32000);
    hipLaunchKernelGGL(transpose_f32_kernel,   dim3(2, 16),   dim3(256), 0, stream, Wq,    WqT,    512, 64);

    // --- embedding gathers + zero h + zero barrier counters ---
    hipLaunchKernelGGL(gather_init_kernel, dim3(4193), dim3(256), 0, stream,
                       src, trg, enc_embed, dec_embed, embE, embD, hF, hB, bar);

    // --- input-projection GEMMs (all timesteps batched) ---
    hipLaunchKernelGGL(gemm_bf16x3_kernel, dim3(12, 16), dim3(256), 0, stream,
                       embE, WiF_hi, WiF_lo, bi_f, giF, 2048, 1536, 256, 0, 0, 1);
    hipLaunchKernelGGL(gemm_bf16x3_kernel, dim3(12, 16), dim3(256), 0, stream,
                       embE, WiB_hi, WiB_lo, bi_b, giB, 2048, 1536, 256, 0, 0, 1);
    hipLaunchKernelGGL(gemm_bf16x3_kernel, dim3(12, 16), dim3(256), 0, stream,
                       embD, WiD_hi, WiD_lo, bi_d, giD, 2016, 1536, 256, 0, 0, 1);

    // --- encoder recurrence: ONE persistent cooperative kernel ---
    {
        void* eargs[] = { (void*)&hF, (void*)&hB, (void*)&giF, (void*)&giB,
                          (void*)&Wh_f, (void*)&Wh_b, (void*)&bh_f, (void*)&bh_b,
                          (void*)&src_lens, (void*)&wrep, (void*)&sent, (void*)&bar };
        hipLaunchCooperativeKernel((const void*)enc_persistent_kernel,
                                   dim3(128), dim3(256), eargs, 0, stream);
    }

    // --- K/V projections, decoder init state ---
    hipLaunchKernelGGL(gemm_bf16x3_kernel, dim3(1, 16), dim3(256), 0, stream,
                       wrep, Wk_hi, Wk_lo, bk, Kmat, 2048, 64, 1024, 0, 0, 0);
    hipLaunchKernelGGL(gemm_bf16x3_kernel, dim3(4, 16), dim3(256), 0, stream,
                       wrep, Wv_hi, Wv_lo, bv, Vmat, 2048, 512, 1024, 0, 0, 1);
    hipLaunchKernelGGL(gemm_bf16x3_kernel, dim3(4, 1), dim3(256), 0, stream,
                       sent, We_hi, We_lo, b_e2d, HID, 32, 512, 1024, 1, 0, 0);

    // --- decoder recurrence: ONE persistent cooperative kernel ---
    {
        unsigned* barD = bar + 1;
        void* dargs[] = { (void*)&HID, (void*)&giD, (void*)&Wh_d, (void*)&bh_d,
                          (void*)&Kmat, (void*)&Vmat, (void*)&WqT, (void*)&bq,
                          (void*)&htmp, (void*)&barD };
        hipLaunchCooperativeKernel((const void*)dec_persistent_kernel,
                                   dim3(64), dim3(256), dargs, 0, stream);
    }

    // --- output projection: G1 = gelu(HID[1:] @ W1 + b1); OUT = G1 @ W2 + b2 ---
    hipLaunchKernelGGL(gemm_bf16x3_kernel, dim3(4, 16), dim3(256), 0, stream,
                       HID + 16384, W1_hi, W1_lo, b1, G1, 2016, 512, 512, 1, 0, 1);
    hipLaunchKernelGGL(gemm_bf16x3_kernel, dim3(250, 16), dim3(256), 0, stream,
                       G1, W2_hi, W2_lo, b2, out, 2016, 32000, 512, 0, 1, 1);

    // --- out[:, 0, :] = 0 ---
    hipLaunchKernelGGL(zero_col0_kernel, dim3(4000), dim3(256), 0, stream, out);
}